// Round 20
// baseline (303.699 us; speedup 1.0000x reference)
//
#include <hip/hip_runtime.h>
#include <math.h>

// Problem constants
#define LL   4096      // H*W
#define DI   128       // 2*C
#define CC   64        // C
#define BB   8         // batch
#define KK   4         // scan directions
#define LB   32768     // pixels per instance
#define NPIX 2097152   // B*H*W*C elements of s
#define EPSF 1e-5f

// Workspace layout (float-indexed offsets; most regions hold bf16 now).
#define OFF_XCIN   ((size_t)0)
#define OFF_XCONV  ((size_t)4194304)
#define OFF_XCONVT ((size_t)8388608)
#define OFF_Z      ((size_t)12582912)
#define OFF_Y      ((size_t)16777216)
#define OFF_YT     ((size_t)20971520)
#define OFF_XDBL   ((size_t)25165824)
#define ISTRIDE    ((size_t)25952256)   // floats per instance
// Aliases (lifetime-disjoint reuse):
#define OFF_YCOMBT OFF_XCIN             // xcin dead after k2; ycombT (d-major) by k3c
#define OFF_SB     OFF_Y                // y dead after k3c; sbuf by fused k4

typedef short v8s __attribute__((ext_vector_type(8)));
typedef float v4f __attribute__((ext_vector_type(4)));

__device__ __forceinline__ float fexp_(float x){ return __expf(x); }
__device__ __forceinline__ float silu_(float x){ return __fdividef(x, 1.f+__expf(-x)); }
__device__ __forceinline__ float softplusf_(float x){
  return fmaxf(x,0.f) + __logf(1.f + __expf(-fabsf(x)));
}
// Fast erf (Abramowitz-Stegun 7.1.26, |err| < 1.5e-7) with native exp
__device__ __forceinline__ float erf_fast_(float x){
  const float ax = fabsf(x);
  const float t = __fdividef(1.f, 1.f + 0.3275911f*ax);
  const float poly = t*(0.254829592f + t*(-0.284496736f + t*(1.421413741f +
                     t*(-1.453152027f + t*1.061405429f))));
  const float e = 1.f - poly*__expf(-ax*ax);
  return copysignf(e, x);
}
__device__ __forceinline__ float geluf_(float x){ return 0.5f*x*(1.f+erf_fast_(x*0.70710678118f)); }
__device__ __forceinline__ short bf16_(float x){
  unsigned u = __float_as_uint(x);
  u += 0x7FFF + ((u>>16)&1);     // RNE
  return (short)(u>>16);
}
__device__ __forceinline__ float bf2f_(short s){
  return __uint_as_float(((unsigned)(unsigned short)s)<<16);
}

#define LD16(dst, ptr) { const float4* p4_=(const float4*)(ptr);                 \
  float4 v0_=p4_[0], v1_=p4_[1], v2_=p4_[2], v3_=p4_[3];                         \
  dst[0]=v0_.x; dst[1]=v0_.y; dst[2]=v0_.z; dst[3]=v0_.w;                        \
  dst[4]=v1_.x; dst[5]=v1_.y; dst[6]=v1_.z; dst[7]=v1_.w;                        \
  dst[8]=v2_.x; dst[9]=v2_.y; dst[10]=v2_.z; dst[11]=v2_.w;                      \
  dst[12]=v3_.x; dst[13]=v3_.y; dst[14]=v3_.z; dst[15]=v3_.w; }
// 16 bf16 (32B) -> 16 floats
#define LD16H(dst, ptr) { const v8s* p8_=(const v8s*)(ptr);                      \
  v8s a0_=p8_[0], a1_=p8_[1];                                                    \
  _Pragma("unroll") for(int e_=0;e_<8;++e_){ dst[e_]=bf2f_(a0_[e_]);             \
                                             dst[8+e_]=bf2f_(a1_[e_]); } }
// 16 bf16 reversed: dst[15-m] = ptr[m]
#define LD16HR(dst, ptr) { const v8s* p8_=(const v8s*)(ptr);                     \
  v8s a0_=p8_[0], a1_=p8_[1];                                                    \
  _Pragma("unroll") for(int e_=0;e_<8;++e_){ dst[15-e_]=bf2f_(a0_[e_]);          \
                                             dst[7-e_]=bf2f_(a1_[e_]); } }
// 16 floats -> 16 bf16 (2 v8s stores)
#define ST16H(ptr, srcv) { v8s o0_, o1_;                                         \
  _Pragma("unroll") for(int e_=0;e_<8;++e_){ o0_[e_]=bf16_(srcv[e_]);            \
                                             o1_[e_]=bf16_(srcv[8+e_]); }        \
  ((v8s*)(ptr))[0]=o0_; ((v8s*)(ptr))[1]=o1_; }

// K1 (MFMA): block = 64 pixels, 4 waves; LN -> bf16 hlds; ipw staged per half;
// outputs xcin (bf16, b,d,l) and zT (bf16, d-major silu).
__global__ __launch_bounds__(256) void k1_ln_inproj(
    const float* __restrict__ xmag, const float* __restrict__ xph,
    const float* __restrict__ n1w_, const float* __restrict__ n1b_,
    const float* __restrict__ ipw_, float* __restrict__ ws)
{
  const int i = blockIdx.y;
  const float* xin = i ? xph : xmag;
  const float* n1w = n1w_ + i*CC;
  const float* n1b = n1b_ + i*CC;
  const float* ipw = ipw_ + i*2*DI*CC;   // [256][64]
  float* base = ws + (size_t)i*ISTRIDE;
  const int t = threadIdx.x, lane = t & 63;
  const int wv = __builtin_amdgcn_readfirstlane(t >> 6);
  const int m = lane & 15, quad = lane >> 4;
  const int p0 = blockIdx.x*64;
  const int b = p0 >> 12, l0 = p0 & (LL-1);

  __shared__ short hlds[64*72];
  __shared__ short w1lds[128*72];
  __shared__ float outs[128*68];

  {
    float hn[CC];
    const float* xr = xin + (size_t)(p0 + lane)*CC;
    LD16(hn, xr); LD16((hn+16), xr+16); LD16((hn+32), xr+32); LD16((hn+48), xr+48);
    float s1=0.f, s2=0.f;
    #pragma unroll
    for(int c=0;c<CC;++c){ s1 += hn[c]; s2 += hn[c]*hn[c]; }
    const float mu = s1*(1.f/CC);
    const float rs = rsqrtf(s2*(1.f/CC) - mu*mu + EPSF);
    if(wv==0){
      #pragma unroll
      for(int q=0;q<8;++q){
        v8s s;
        #pragma unroll
        for(int e=0;e<8;++e){
          const int c = q*8+e;
          s[e] = bf16_((hn[c]-mu)*rs*n1w[c] + n1b[c]);
        }
        *(v8s*)&hlds[lane*72 + q*8] = s;
      }
    }
  }

  for(int h=0; h<2; ++h){
    if(h) __syncthreads();
    {
      const int jl = t >> 1, hc = (t & 1)*32;
      const float* src = ipw + (size_t)(h*128 + jl)*64 + hc;
      #pragma unroll
      for(int q=0;q<4;++q){
        const float4 fa = ((const float4*)src)[q*2];
        const float4 fb = ((const float4*)src)[q*2+1];
        v8s s;
        s[0]=bf16_(fa.x); s[1]=bf16_(fa.y); s[2]=bf16_(fa.z); s[3]=bf16_(fa.w);
        s[4]=bf16_(fb.x); s[5]=bf16_(fb.y); s[6]=bf16_(fb.z); s[7]=bf16_(fb.w);
        *(v8s*)&w1lds[jl*72 + hc + q*8] = s;
      }
    }
    __syncthreads();
    #pragma unroll 2
    for(int nt=0; nt<8; ++nt){
      v4f acc = (v4f){0.f,0.f,0.f,0.f};
      #pragma unroll
      for(int ks=0; ks<2; ++ks){
        const v8s a = *(const v8s*)&hlds[(wv*16 + m)*72 + ks*32 + quad*8];
        const v8s bb = *(const v8s*)&w1lds[(nt*16 + m)*72 + ks*32 + quad*8];
        acc = __builtin_amdgcn_mfma_f32_16x16x32_bf16(a, bb, acc, 0, 0, 0);
      }
      *(float4*)&outs[(nt*16 + m)*68 + wv*16 + quad*4] =
          make_float4(acc[0], acc[1], acc[2], acc[3]);
    }
    __syncthreads();
    const int jl = t >> 1, hc = (t & 1)*32;
    if(h==0){
      short* xcb = (short*)(base + OFF_XCIN) + (size_t)b*DI*LL + (size_t)jl*LL + l0 + hc;
      const float* so = &outs[jl*68 + hc];
      ST16H(xcb, so);
      ST16H(xcb+16, (so+16));
    } else {
      short* zr = (short*)(base + OFF_Z) + (size_t)jl*LB + p0 + hc;
      float tmp[32];
      #pragma unroll
      for(int e=0;e<32;++e) tmp[e] = silu_(outs[jl*68 + hc + e]);
      ST16H(zr, tmp);
      ST16H(zr+16, (tmp+16));
    }
  }
}

// K2: depthwise 3x3 conv + silu; bf16 in (xcin), bf16 out (xconv/xconvT).
__global__ __launch_bounds__(256) void k2_dwconv(
    const float* __restrict__ cw_, float* __restrict__ ws)
{
  const int i = blockIdx.y;
  const int bd = blockIdx.x;
  const int d = bd & (DI-1);
  const float* cw = cw_ + i*DI*9 + d*9;
  const short* xcin = (const short*)(ws + (size_t)i*ISTRIDE + OFF_XCIN) + (size_t)bd*LL;
  short* xconv  = (short*)(ws + (size_t)i*ISTRIDE + OFF_XCONV ) + (size_t)bd*LL;
  short* xconvT = (short*)(ws + (size_t)i*ISTRIDE + OFF_XCONVT) + (size_t)bd*LL;
  __shared__ float tin[64*65];
  __shared__ float tout[64*65];
  const int t = threadIdx.x;
  float w9[9];
  #pragma unroll
  for(int q=0;q<9;++q) w9[q] = cw[q];
  for(int idx=t; idx<4096; idx+=256)
    tin[(idx>>6)*65 + (idx&63)] = bf2f_(xcin[idx]);
  __syncthreads();
  const int w = t & 63, hb = (t>>6)*16;
  #pragma unroll
  for(int r=0;r<16;++r){
    const int h = hb + r;
    float acc = 0.f;
    #pragma unroll
    for(int dy=0;dy<3;++dy){
      const int hh = h + dy - 1;
      if(hh>=0 && hh<64){
        #pragma unroll
        for(int dx=0;dx<3;++dx){
          const int ww = w + dx - 1;
          if(ww>=0 && ww<64) acc += tin[hh*65+ww]*w9[dy*3+dx];
        }
      }
    }
    const float o = silu_(acc);
    tout[h*65+w] = o;
    xconv[h*64+w] = bf16_(o);
  }
  __syncthreads();
  const int hcol = t & 63, wb = (t>>6)*16;
  #pragma unroll
  for(int r=0;r<16;++r){
    const int wp = wb + r;
    xconvT[wp*64 + hcol] = bf16_(tout[hcol*65 + wp]);
  }
}

// K3a: paired-direction x_proj from bf16 src; xdbl stored bf16.
__global__ __launch_bounds__(256) void k3a_xproj(
    const float* __restrict__ xpw_, float* __restrict__ ws)
{
  const int i = blockIdx.z;
  const int b = blockIdx.y >> 1;
  const int kp = blockIdx.y & 1;
  const int l = blockIdx.x*256 + threadIdx.x;   // source index
  const short* src = (const short*)(ws + (size_t)i*ISTRIDE + (kp? OFF_XCONVT : OFF_XCONV))
                     + (size_t)b*DI*LL;
  const float* xpwF = xpw_ + i*KK*6*DI + kp*6*DI;
  const float* xpwB = xpw_ + i*KK*6*DI + (kp+2)*6*DI;
  float accF[6] = {0,0,0,0,0,0};
  float accB[6] = {0,0,0,0,0,0};
  for(int d=0; d<DI; ++d){
    const float xv = bf2f_(src[(size_t)d*LL + l]);
    #pragma unroll
    for(int c=0;c<6;++c){
      accF[c] += xv * xpwF[c*DI + d];
      accB[c] += xv * xpwB[c*DI + d];
    }
  }
  short* xdF = (short*)(ws + (size_t)i*ISTRIDE + OFF_XDBL) + (size_t)(b*KK+kp  )*6*LL;
  short* xdB = (short*)(ws + (size_t)i*ISTRIDE + OFF_XDBL) + (size_t)(b*KK+kp+2)*6*LL;
  #pragma unroll
  for(int c=0;c<6;++c) xdF[(size_t)c*LL + l] = bf16_(accF[c]);
  #pragma unroll
  for(int c=0;c<6;++c) xdB[(size_t)c*LL + (LL-1-l)] = bf16_(accB[c]);
}

// K3b: paired fwd/bwd scan (all streams bf16; scan state fp32). (256,3).
__global__ __launch_bounds__(256,3) void k3b_scan(
    const float* __restrict__ dtw_, const float* __restrict__ dtb_,
    const float* __restrict__ alog_, const float* __restrict__ Ds_,
    float* __restrict__ ws)
{
  const int gid = blockIdx.x;           // b*256 + kp*128 + d
  const int i = blockIdx.y;
  const int d  = gid & (DI-1);
  const int kp = (gid >> 7) & 1;
  const int b  = gid >> 8;
  const int t = threadIdx.x, lane = t & 63, wv = t >> 6;
  float* base = ws + (size_t)i*ISTRIDE;
  const short* src = (const short*)(base + (kp? OFF_XCONVT : OFF_XCONV)) + (size_t)(b*DI+d)*LL;
  short*       dst = (short*)(base + (kp? OFF_YT : OFF_Y)) + (size_t)(b*DI+d)*LL;
  const short* xdF = (const short*)(base + OFF_XDBL) + (size_t)(b*KK+kp  )*6*LL;
  const short* xdB = (const short*)(base + OFF_XDBL) + (size_t)(b*KK+kp+2)*6*LL;
  const int kdF = kp*DI + d, kdB = (kp+2)*DI + d;
  const float4 wF = ((const float4*)dtw_)[i*KK*DI + kdF];
  const float4 wB = ((const float4*)dtw_)[i*KK*DI + kdB];
  const float biasF = dtb_[i*KK*DI + kdF], biasB = dtb_[i*KK*DI + kdB];
  const float AvF = -fexp_(alog_[i*KK*DI + kdF]);
  const float AvB = -fexp_(alog_[i*KK*DI + kdB]);
  const float Dsum = Ds_[i*KK*DI + kdF] + Ds_[i*KK*DI + kdB];
  const int l0 = t*16;
  const int s0 = LL - 16 - l0;

  float vX[16], aF[16], bF[16], aB[16], bB[16];
  float fA = 1.f, fB = 0.f, gA = 1.f, gB = 0.f;
  LD16H(vX, src + l0);

  {
    float pre[16], r0[16];
    LD16H(r0, xdF + 0*LL + l0);
    #pragma unroll
    for(int j=0;j<16;++j) pre[j] = biasF + wF.x*r0[j];
    LD16H(r0, xdF + 1*LL + l0);
    #pragma unroll
    for(int j=0;j<16;++j) pre[j] += wF.y*r0[j];
    LD16H(r0, xdF + 2*LL + l0);
    #pragma unroll
    for(int j=0;j<16;++j) pre[j] += wF.z*r0[j];
    LD16H(r0, xdF + 3*LL + l0);
    #pragma unroll
    for(int j=0;j<16;++j) pre[j] += wF.w*r0[j];
    LD16H(r0, xdF + 4*LL + l0);   // Bs
    #pragma unroll
    for(int j=0;j<16;++j){
      const float delta = softplusf_(pre[j]);
      aF[j] = fexp_(delta*AvF);
      bF[j] = delta*r0[j]*vX[j];
      fB = fB*aF[j] + bF[j];
      fA *= aF[j];
    }
  }
  {
    float pre[16], r0[16];
    LD16HR(r0, xdB + 0*LL + s0);
    #pragma unroll
    for(int j=0;j<16;++j) pre[j] = biasB + wB.x*r0[j];
    LD16HR(r0, xdB + 1*LL + s0);
    #pragma unroll
    for(int j=0;j<16;++j) pre[j] += wB.y*r0[j];
    LD16HR(r0, xdB + 2*LL + s0);
    #pragma unroll
    for(int j=0;j<16;++j) pre[j] += wB.z*r0[j];
    LD16HR(r0, xdB + 3*LL + s0);
    #pragma unroll
    for(int j=0;j<16;++j) pre[j] += wB.w*r0[j];
    LD16HR(r0, xdB + 4*LL + s0);  // Bs reversed
    #pragma unroll
    for(int j=15;j>=0;--j){
      const float delta = softplusf_(pre[j]);
      aB[j] = fexp_(delta*AvB);
      bB[j] = delta*r0[j]*vX[j];
      gB = gB*aB[j] + bB[j];
      gA *= aB[j];
    }
  }

  #pragma unroll
  for(int off=1; off<64; off<<=1){
    const float aL = __shfl_up(fA, off);
    const float bL = __shfl_up(fB, off);
    if(lane >= off){ fB = bL*fA + fB; fA = aL*fA; }
  }
  float pA = __shfl_up(fA, 1), pB = __shfl_up(fB, 1);
  if(lane==0){ pA=1.f; pB=0.f; }
  #pragma unroll
  for(int off=1; off<64; off<<=1){
    const float aR = __shfl_down(gA, off);
    const float bR = __shfl_down(gB, off);
    if(lane + off < 64){ gB = gA*bR + gB; gA = gA*aR; }
  }
  float qA = __shfl_down(gA, 1), qB = __shfl_down(gB, 1);
  if(lane==63){ qA=1.f; qB=0.f; }

  __shared__ float wAg[4], wBg[4], vAg[4], vBg[4];
  if(lane==63){ wAg[wv]=fA; wBg[wv]=fB; }
  if(lane==0){ vAg[wv]=gA; vBg[wv]=gB; }
  __syncthreads();
  float eB=0.f;
  for(int u=0; u<wv; ++u){ eB = wAg[u]*eB + wBg[u]; }
  float rB=0.f;
  for(int u=3; u>wv; --u){ rB = vAg[u]*rB + vBg[u]; }

  float hf = pA*eB + pB;
  float hb = qA*rB + qB;

  float out[16], cc[16];
  LD16H(cc, xdF + 5*LL + l0);
  #pragma unroll
  for(int j=0;j<16;++j){
    hf = aF[j]*hf + bF[j];
    out[j] = hf*cc[j] + Dsum*vX[j];
  }
  LD16HR(cc, xdB + 5*LL + s0);
  #pragma unroll
  for(int j=15;j>=0;--j){
    hb = aB[j]*hb + bB[j];
    out[j] += hb*cc[j];
  }
  ST16H(dst + l0, out);
}

// K3c: combine y + transpose(yT) (bf16 in) into d-major bf16 ycombT[d][b*LL+l].
__global__ __launch_bounds__(256) void k3c_combine(float* __restrict__ ws)
{
  const int i = blockIdx.y;
  const int b = blockIdx.x >> 4;
  const int tile = blockIdx.x & 15;
  const int h0 = (tile >> 2) * 16, w0 = (tile & 3) * 16;
  const int t = threadIdx.x;
  float* base = ws + (size_t)i*ISTRIDE;
  const short* y  = (const short*)(base + OFF_Y);
  const short* yT = (const short*)(base + OFF_YT);
  short* ycT = (short*)(base + OFF_YCOMBT);
  __shared__ float ytile[16*16*16];
  __shared__ float ytT[16*16*17];
  const int r0 = t >> 4, c0 = t & 15;
  const int hi = t >> 4, wi = t & 15;
  const int l = (h0 + hi)*64 + (w0 + wi);
  for(int dc=0; dc<8; ++dc){
    #pragma unroll 4
    for(int dd=0; dd<16; ++dd){
      const int d = dc*16 + dd;
      const size_t rb = (size_t)(b*DI + d)*LL;
      ytile[dd*256 + t] = bf2f_(y[rb + (size_t)(h0 + r0)*64 + (w0 + c0)]);
      ytT[dd*272 + r0*17 + c0] = bf2f_(yT[rb + (size_t)(w0 + r0)*64 + (h0 + c0)]);
    }
    __syncthreads();
    #pragma unroll 4
    for(int dd=0; dd<16; ++dd){
      const int d = dc*16 + dd;
      ycT[(size_t)d*LB + b*LL + l] = bf16_(ytile[dd*256 + t] + ytT[dd*272 + wi*17 + hi]);
    }
    __syncthreads();
  }
}

// K4 fused (MFMA): block = 64 pixels, 4 waves.
// Phase A (was k4a): LN(ycomb)*z -> ynlds; out_proj mfma; xnew = acc + xin kept
// in C-layout registers AND written bf16 to xnlds.
// Phase B (was k4b): LN(xnlds) -> hlds; fc1+GELU(fast erf) -> glds; fc2 mfma;
// epilogue sbuf = acc2 + f2b + xnewC (regs). No global xnew round-trip.
__global__ __launch_bounds__(256) void k4_fused(
    const float* __restrict__ xmag, const float* __restrict__ xph,
    const float* __restrict__ onw_, const float* __restrict__ onb_,
    const float* __restrict__ opw_,
    const float* __restrict__ n2w_, const float* __restrict__ n2b_,
    const float* __restrict__ f1w_, const float* __restrict__ f1b_,
    const float* __restrict__ f2w_, const float* __restrict__ f2b_,
    float* __restrict__ ws)
{
  const int i = blockIdx.y;
  const float* xin = i ? xph : xmag;
  const float* onw = onw_ + i*DI;
  const float* onb = onb_ + i*DI;
  const float* opw = opw_ + i*CC*DI;     // [o][d] = [64][128]
  const float* n2w = n2w_ + i*CC;
  const float* n2b = n2b_ + i*CC;
  const float* f1w = f1w_ + i*256*64;    // [j][c]
  const float* f1b = f1b_ + i*256;
  const float* f2w = f2w_ + i*64*256;    // [o][j]
  const float* f2b = f2b_ + i*CC;
  float* base = ws + (size_t)i*ISTRIDE;
  const short* ycT = (const short*)(base + OFF_YCOMBT);
  const short* zT  = (const short*)(base + OFF_Z);
  const int t = threadIdx.x, lane = t & 63;
  const int wv = __builtin_amdgcn_readfirstlane(t >> 6);
  const int m = lane & 15, quad = lane >> 4;
  const int p0 = blockIdx.x*64;
  const int p = p0 + lane;

  // LDS pool (explicit union; 71680 B total -> 2 blocks/CU)
  __shared__ __align__(16) char pool[71680];
  short* xnlds = (short*)(pool);              // [64][72] bf16, persistent A->B
  // phase A:
  short* ynlds = (short*)(pool + 9216);       // [64][136]
  short* wlds  = (short*)(pool + 26624);      // [64][136]
  float (*st)[9] = (float(*)[9])(pool + 44032); // [64][9]
  // phase B:
  short* hlds  = (short*)(pool + 9216);       // [64][72]  (reuses ynlds region)
  short* w1lds = (short*)(pool + 18432);      // [128][72]
  short* glds  = (short*)(pool + 36864);      // [64][136]
  short* w2lds = (short*)(pool + 54272);      // [64][136]

  // ---------------- Phase A: out_norm*z + out_proj ----------------
  {
    float yv[32];
    float s1=0.f, s2=0.f;
    #pragma unroll 8
    for(int c=0;c<32;++c){
      const float v = bf2f_(ycT[(size_t)(wv*32+c)*LB + p]);
      yv[c]=v; s1+=v; s2+=v*v;
    }
    st[lane][wv*2]=s1; st[lane][wv*2+1]=s2;
    __syncthreads();
    const float S1 = st[lane][0]+st[lane][2]+st[lane][4]+st[lane][6];
    const float S2 = st[lane][1]+st[lane][3]+st[lane][5]+st[lane][7];
    const float mu = S1*(1.f/DI);
    const float rs = rsqrtf(S2*(1.f/DI) - mu*mu + EPSF);
    #pragma unroll
    for(int cq=0;cq<8;++cq){
      short4 s4;
      #pragma unroll
      for(int e=0;e<4;++e){
        const int c = cq*4+e;
        const int d = wv*32 + c;
        ((short*)&s4)[e] = bf16_(((yv[c]-mu)*rs*onw[d] + onb[d]) * bf2f_(zT[(size_t)d*LB + p]));
      }
      *(short4*)&ynlds[lane*136 + wv*32 + cq*4] = s4;
    }
  }
  {
    const int ol = t >> 2, seg = (t & 3)*32;
    const float* src = opw + (size_t)ol*DI + seg;
    #pragma unroll
    for(int q=0;q<4;++q){
      const float4 fa = ((const float4*)src)[q*2];
      const float4 fb = ((const float4*)src)[q*2+1];
      v8s s;
      s[0]=bf16_(fa.x); s[1]=bf16_(fa.y); s[2]=bf16_(fa.z); s[3]=bf16_(fa.w);
      s[4]=bf16_(fb.x); s[5]=bf16_(fb.y); s[6]=bf16_(fb.z); s[7]=bf16_(fb.w);
      *(v8s*)&wlds[ol*136 + seg + q*8] = s;
    }
  }
  __syncthreads();

  float xnC[16];   // xnew in C-layout regs: [nt][r] at (px = wv*16+quad*4+r, o = nt*16+m)
  #pragma unroll
  for(int nt=0; nt<4; ++nt){
    v4f acc = (v4f){0.f,0.f,0.f,0.f};
    #pragma unroll
    for(int ks=0; ks<4; ++ks){
      const v8s a = *(const v8s*)&ynlds[(wv*16 + m)*136 + ks*32 + quad*8];
      const v8s b = *(const v8s*)&wlds[(nt*16 + m)*136 + ks*32 + quad*8];
      acc = __builtin_amdgcn_mfma_f32_16x16x32_bf16(a, b, acc, 0, 0, 0);
    }
    #pragma unroll
    for(int r=0;r<4;++r){
      const int pp = p0 + wv*16 + quad*4 + r;
      const int o = nt*16 + m;
      xnC[nt*4+r] = acc[r] + xin[(size_t)pp*CC + o];
    }
  }
  __syncthreads();                 // ynlds/wlds dead; B regions may now be written
  // write xnew tile to LDS for phase-B LN (scalar bf16 stores, C-layout positions)
  #pragma unroll
  for(int nt=0; nt<4; ++nt){
    #pragma unroll
    for(int r=0;r<4;++r){
      xnlds[(wv*16 + quad*4 + r)*72 + nt*16 + m] = bf16_(xnC[nt*4+r]);
    }
  }
  __syncthreads();

  // ---------------- Phase B: LN2 + MLP ----------------
  {
    float h2[64];
    const short* xr = xnlds + lane*72;
    LD16H(h2, xr); LD16H((h2+16), xr+16); LD16H((h2+32), xr+32); LD16H((h2+48), xr+48);
    float s1=0.f, s2=0.f;
    #pragma unroll
    for(int c=0;c<CC;++c){ s1 += h2[c]; s2 += h2[c]*h2[c]; }
    const float mu = s1*(1.f/CC);
    const float rs = rsqrtf(s2*(1.f/CC) - mu*mu + EPSF);
    if(wv==0){
      #pragma unroll
      for(int q=0;q<8;++q){
        v8s s;
        #pragma unroll
        for(int e=0;e<8;++e){
          const int c = q*8+e;
          s[e] = bf16_((h2[c]-mu)*rs*n2w[c] + n2b[c]);
        }
        *(v8s*)&hlds[lane*72 + q*8] = s;
      }
    }
  }

  v4f acc2[4];
  #pragma unroll
  for(int n=0;n<4;++n) acc2[n] = (v4f){0.f,0.f,0.f,0.f};

  for(int h=0; h<2; ++h){
    __syncthreads();               // h=0: hlds visible; h=1: prev fc2 reads done
    {
      const int jl = t >> 1, hc = (t & 1)*32;
      const float* src = f1w + (size_t)(h*128 + jl)*64 + hc;
      #pragma unroll
      for(int q=0;q<4;++q){
        const float4 fa = ((const float4*)src)[q*2];
        const float4 fb = ((const float4*)src)[q*2+1];
        v8s s;
        s[0]=bf16_(fa.x); s[1]=bf16_(fa.y); s[2]=bf16_(fa.z); s[3]=bf16_(fa.w);
        s[4]=bf16_(fb.x); s[5]=bf16_(fb.y); s[6]=bf16_(fb.z); s[7]=bf16_(fb.w);
        *(v8s*)&w1lds[jl*72 + hc + q*8] = s;
      }
    }
    {
      const int ol = t >> 2, seg = (t & 3)*32;
      const float* src = f2w + (size_t)ol*256 + h*128 + seg;
      #pragma unroll
      for(int q=0;q<4;++q){
        const float4 fa = ((const float4*)src)[q*2];
        const float4 fb = ((const float4*)src)[q*2+1];
        v8s s;
        s[0]=bf16_(fa.x); s[1]=bf16_(fa.y); s[2]=bf16_(fa.z); s[3]=bf16_(fa.w);
        s[4]=bf16_(fb.x); s[5]=bf16_(fb.y); s[6]=bf16_(fb.z); s[7]=bf16_(fb.w);
        *(v8s*)&w2lds[ol*136 + seg + q*8] = s;
      }
    }
    __syncthreads();
    #pragma unroll 2
    for(int nt=0; nt<8; ++nt){
      v4f acc = (v4f){0.f,0.f,0.f,0.f};
      #pragma unroll
      for(int ks=0; ks<2; ++ks){
        const v8s a = *(const v8s*)&hlds[(wv*16 + m)*72 + ks*32 + quad*8];
        const v8s b = *(const v8s*)&w1lds[(nt*16 + m)*72 + ks*32 + quad*8];
        acc = __builtin_amdgcn_mfma_f32_16x16x32_bf16(a, b, acc, 0, 0, 0);
      }
      const float bj = f1b[h*128 + nt*16 + m];
      #pragma unroll
      for(int r=0;r<4;++r){
        glds[(wv*16 + quad*4 + r)*136 + nt*16 + m] = bf16_(geluf_(acc[r] + bj));
      }
    }
    #pragma unroll
    for(int nt=0; nt<4; ++nt){
      v4f acc = acc2[nt];
      #pragma unroll
      for(int ks=0; ks<4; ++ks){
        const v8s a = *(const v8s*)&glds[(wv*16 + m)*136 + ks*32 + quad*8];
        const v8s b = *(const v8s*)&w2lds[(nt*16 + m)*136 + ks*32 + quad*8];
        acc = __builtin_amdgcn_mfma_f32_16x16x32_bf16(a, b, acc, 0, 0, 0);
      }
      acc2[nt] = acc;
    }
  }

  short* sb = (short*)(base + OFF_SB);
  #pragma unroll
  for(int nt=0; nt<4; ++nt){
    const float bo = f2b[nt*16 + m];
    #pragma unroll
    for(int r=0;r<4;++r){
      const int pp = p0 + wv*16 + quad*4 + r;
      const int o = nt*16 + m;
      sb[(size_t)pp*CC + o] = bf16_(acc2[nt][r] + bo + xnC[nt*4+r]);
    }
  }
}

// K5: s = inst0 + inst1 (bf16 in, fp32 out); 8 elems/thread; both output halves
__global__ __launch_bounds__(256) void k5_final(
    const float* __restrict__ ws, float* __restrict__ out)
{
  const int idx = blockIdx.x*256 + threadIdx.x;   // v8s index
  const v8s a = ((const v8s*)(ws + OFF_SB))[idx];
  const v8s b = ((const v8s*)(ws + ISTRIDE + OFF_SB))[idx];
  float4 v0, v1;
  v0.x = bf2f_(a[0])+bf2f_(b[0]); v0.y = bf2f_(a[1])+bf2f_(b[1]);
  v0.z = bf2f_(a[2])+bf2f_(b[2]); v0.w = bf2f_(a[3])+bf2f_(b[3]);
  v1.x = bf2f_(a[4])+bf2f_(b[4]); v1.y = bf2f_(a[5])+bf2f_(b[5]);
  v1.z = bf2f_(a[6])+bf2f_(b[6]); v1.w = bf2f_(a[7])+bf2f_(b[7]);
  ((float4*)out)[idx*2]   = v0;
  ((float4*)out)[idx*2+1] = v1;
  ((float4*)out)[NPIX/4 + idx*2]   = v0;
  ((float4*)out)[NPIX/4 + idx*2+1] = v1;
}

extern "C" void kernel_launch(void* const* d_in, const int* in_sizes, int n_in,
                              void* d_out, int out_size, void* d_ws, size_t ws_size,
                              hipStream_t stream)
{
  const float* mag  = (const float*)d_in[0];
  const float* ph   = (const float*)d_in[1];
  const float* n1w  = (const float*)d_in[2];
  const float* n1b  = (const float*)d_in[3];
  const float* ipw  = (const float*)d_in[4];
  const float* cw   = (const float*)d_in[5];
  const float* xpw  = (const float*)d_in[6];
  const float* dtw  = (const float*)d_in[7];
  const float* dtb  = (const float*)d_in[8];
  const float* alog = (const float*)d_in[9];
  const float* Ds   = (const float*)d_in[10];
  const float* onw  = (const float*)d_in[11];
  const float* onb  = (const float*)d_in[12];
  const float* opw  = (const float*)d_in[13];
  const float* n2w  = (const float*)d_in[14];
  const float* n2b  = (const float*)d_in[15];
  const float* f1w  = (const float*)d_in[16];
  const float* f1b  = (const float*)d_in[17];
  const float* f2w  = (const float*)d_in[18];
  const float* f2b  = (const float*)d_in[19];
  float* ws = (float*)d_ws;
  float* out = (float*)d_out;

  k1_ln_inproj<<<dim3(512,2),  256, 0, stream>>>(mag, ph, n1w, n1b, ipw, ws);
  k2_dwconv   <<<dim3(1024,2), 256, 0, stream>>>(cw, ws);
  k3a_xproj   <<<dim3(16,16,2),256, 0, stream>>>(xpw, ws);
  k3b_scan    <<<dim3(2048,2), 256, 0, stream>>>(dtw, dtb, alog, Ds, ws);
  k3c_combine <<<dim3(128,2),  256, 0, stream>>>(ws);
  k4_fused    <<<dim3(512,2),  256, 0, stream>>>(mag, ph, onw, onb, opw,
                                                 n2w, n2b, f1w, f1b, f2w, f2b, ws);
  k5_final    <<<dim3(1024),   256, 0, stream>>>(ws, out);
}